// Round 20
// baseline (118.080 us; speedup 1.0000x reference)
//
#include <hip/hip_runtime.h>
#include <hip/hip_bf16.h>
#include <stdint.h>

#define NB 1024          // B molecules
#define LMAX 160
#define DIM 128
#define NH 4
#define HDIM 32
#define ATT_SCALE 0.1767766952966369f   // 32^-0.5
#define LN_EPS 1e-5f
#define VTP 164          // V^T LDS pitch (u16): conflict-free b64 reads
#define PSP 40           // P LDS pitch (u16)
#define WTP 136          // W^T LDS pitch (u16): 272B rows, 16B-aligned, 2-way banks

typedef __attribute__((ext_vector_type(8))) short bf16x8;
typedef __attribute__((ext_vector_type(4))) float f32x4;

union U8 { uint2 u[2]; uint4 q; bf16x8 v; };

__device__ __forceinline__ ushort f2bf(float f) {
    uint32_t x = __float_as_uint(f);
    x += 0x7fffu + ((x >> 16) & 1u);   // round-to-nearest-even
    return (ushort)(x >> 16);
}
__device__ __forceinline__ uint32_t pk2bf(float a, float b) {
    return (uint32_t)f2bf(a) | ((uint32_t)f2bf(b) << 16);
}
// HW-packed bf16 conversion (v_cvt_pk_bf16_f32): 1 op for 2 values.
__device__ __forceinline__ uint32_t pkcvt(float a, float b) {
    __hip_bfloat162 h = __float22bfloat162_rn(make_float2(a, b));
    return *reinterpret_cast<uint32_t*>(&h);
}

// Workgroup barrier without the vmcnt(0) store drain (R13-verified safe).
__device__ __forceinline__ void wgbar_noflush() {
    asm volatile("s_waitcnt lgkmcnt(0)" ::: "memory");
    __builtin_amdgcn_s_barrier();
    asm volatile("" ::: "memory");
}

// ---------------------------------------------------------------------------
// K0: merged setup (weights transpose + segment binary search).
// ---------------------------------------------------------------------------
__global__ void setup_kernel(const float* __restrict__ Wq, const float* __restrict__ Wk,
                             const float* __restrict__ Wv, const float* __restrict__ Wo,
                             ushort* __restrict__ wtg,
                             const int* __restrict__ bd, const int* __restrict__ ba,
                             int* __restrict__ starts, int* __restrict__ counts, int N)
{
    int t = blockIdx.x * blockDim.x + threadIdx.x;   // 65536 threads
    {   // weight transpose (all threads)
        int m = t >> 14;
        int idx = t & 16383;
        int k = idx >> 7, c = idx & 127;
        const float* W = (m == 0) ? Wq : (m == 1) ? Wk : (m == 2) ? Wv : Wo;
        wtg[(m << 14) + c * DIM + k] = f2bf(W[idx]);
    }
    if (t < 2 * NB) {    // segment search (first 2048 threads)
        int side = t >> 10;
        int b = t & (NB - 1);
        const int* arr = side ? ba : bd;
        int lo = 0, hi = N;
        while (lo < hi) { int mid = (lo + hi) >> 1; if (arr[mid] < b) lo = mid + 1; else hi = mid; }
        int st = lo;
        hi = N;
        while (lo < hi) { int mid = (lo + hi) >> 1; if (arr[mid] < b + 1) lo = mid + 1; else hi = mid; }
        starts[t] = st;
        counts[t] = lo - st;
    }
}

// ---------------------------------------------------------------------------
// K1: MFMA projections, 8-wave blocks, coalesced LDS-repack epilogue (R19).
// NEW: Q (w==0) is written PRE-SCALED by ATT_SCALE, so attn's inner loop
// drops the per-score multiply (bf16 relative precision unchanged).
// ---------------------------------------------------------------------------
__global__ __launch_bounds__(512) void proj_mfma(
    const float* __restrict__ x_don, const float* __restrict__ x_acc,
    const ushort* __restrict__ wtg,
    const float* __restrict__ bq, const float* __restrict__ bk, const float* __restrict__ bv,
    ushort* __restrict__ qkv, int N)
{
    __shared__ ushort wt[128][WTP];
    const int side = blockIdx.y;
    const float* x = side ? x_acc : x_don;
    const int t = threadIdx.x;
    const int lane = t & 63, wid = t >> 6;           // 8 waves
    const int r16 = lane & 15, kg = lane >> 4;
    const int wr0 = blockIdx.x * 128 + wid * 16;     // this wave's 16 rows

    float4 raw[4][2];
    {
        const float* xr = &x[(size_t)(wr0 + r16) * DIM + kg * 8];
        #pragma unroll
        for (int ks = 0; ks < 4; ++ks) {
            raw[ks][0] = *reinterpret_cast<const float4*>(xr + ks * 32);
            raw[ks][1] = *reinterpret_cast<const float4*>(xr + ks * 32 + 4);
        }
    }
    U8 xb[4];
    #pragma unroll
    for (int ks = 0; ks < 4; ++ks) {
        xb[ks].u[0].x = pk2bf(raw[ks][0].x, raw[ks][0].y);
        xb[ks].u[0].y = pk2bf(raw[ks][0].z, raw[ks][0].w);
        xb[ks].u[1].x = pk2bf(raw[ks][1].x, raw[ks][1].y);
        xb[ks].u[1].y = pk2bf(raw[ks][1].z, raw[ks][1].w);
    }

    for (int w = 0; w < 3; ++w) {
        if (w) wgbar_noflush();                      // repack reads done, wt free
        const ushort* wsrc = wtg + ((size_t)w << 14);
        #pragma unroll
        for (int p = 0; p < 4; ++p) {                // 512 thr x 4 x 8 u16 = 16384
            int lin = (p * 512 + t) * 8;
            int c = lin >> 7, k = lin & 127;
            *reinterpret_cast<uint4*>(&wt[c][k]) =
                *reinterpret_cast<const uint4*>(&wsrc[c * DIM + k]);
        }
        wgbar_noflush();                             // wt staged

        f32x4 acc[8];
        #pragma unroll
        for (int j = 0; j < 8; ++j) acc[j] = (f32x4){0.f, 0.f, 0.f, 0.f};

        #pragma unroll
        for (int ks = 0; ks < 4; ++ks)
            #pragma unroll
            for (int ct = 0; ct < 8; ++ct) {
                bf16x8 bfr = *reinterpret_cast<const bf16x8*>(
                    &wt[ct * 16 + r16][ks * 32 + kg * 8]);
                acc[ct] = __builtin_amdgcn_mfma_f32_16x16x32_bf16(xb[ks].v, bfr, acc[ct], 0, 0, 0);
            }

        const float* bias = (w == 0) ? bq : (w == 1) ? bk : bv;
        const float sc = (w == 0) ? ATT_SCALE : 1.f; // pre-scale Q
        float b8[8];
        #pragma unroll
        for (int ct = 0; ct < 8; ++ct) b8[ct] = bias[ct * 16 + r16];

        wgbar_noflush();                             // C: all waves done reading wt

        // ---- scatter into own 16-row quarter (VERIFIED D layout)
        #pragma unroll
        for (int ct = 0; ct < 8; ++ct)
            #pragma unroll
            for (int j = 0; j < 4; ++j)
                wt[wid * 16 + kg * 4 + j][ct * 16 + r16] =
                    f2bf((acc[ct][j] + b8[ct]) * sc);

        // ---- read back full rows (same-wave DS ordering) -> dense dwordx4
        ushort* outp = qkv + (size_t)(side * 3 + w) * N * DIM;
        const int lr4 = lane >> 4;                   // 0..3
        const int c8 = (lane & 15) * 8;              // u16 col (16B chunk)
        #pragma unroll
        for (int ps = 0; ps < 4; ++ps) {
            int lr = ps * 4 + lr4;                   // local row 0..15
            uint4 vv = *reinterpret_cast<const uint4*>(&wt[wid * 16 + lr][c8]);
            *reinterpret_cast<uint4*>(&outp[(size_t)(wr0 + lr) * DIM + c8]) = vv;
        }
    }
}

// ---------------------------------------------------------------------------
// K2: swapped-operand MFMA cross attention, grid (B, 2), WAVE = HEAD (R3's
// verified block shape): V^T staged ONCE per (b,dir) by all 4 waves (staging
// work /4 vs per-head blocks), each wave runs the full q-loop for its head.
// Math = R18/R19 verified: slim softmax (no max machinery), ones-MFMA
// denominator, pkcvt packing, full/tail chunk split.  Q arrives pre-scaled.
// LDS 47.1KB -> 3 blocks/CU.
// ---------------------------------------------------------------------------
__global__ __launch_bounds__(256) void attn_mfma(
    ushort* __restrict__ qkv,
    const int* __restrict__ starts, const int* __restrict__ counts, int N)
{
    __shared__ __align__(16) ushort Vt[128][VTP];    // V^T, ALL heads
    __shared__ __align__(16) ushort Ps[4][16][PSP];  // P round-trip, per wave
    const int b = blockIdx.x, dir = blockIdx.y;
    const int qside = dir, kside = 1 - dir;
    const int qs = starts[qside * NB + b];
    const int nq = counts[qside * NB + b];
    if (nq == 0) return;
    const int kst = starts[kside * NB + b];
    const int nk = min(counts[kside * NB + b], LMAX);
    ushort* Q = qkv + (size_t)(qside * 3) * N * DIM;
    const ushort* K = qkv + (size_t)(kside * 3 + 1) * N * DIM;
    const ushort* V = qkv + (size_t)(kside * 3 + 2) * N * DIM;
    const int t = threadIdx.x;                       // 0..255
    const int lane = t & 63, wid = t >> 6;
    const int r16 = lane & 15, g = lane >> 4;
    const int hcol = wid * HDIM;                     // this wave's head columns

    const int NCK = (nk + 31) >> 5;
    const int NKP = NCK << 5;
    const int NFULL = nk >> 5;                       // unmasked 32-k chunks
    const bool tail = (nk & 31) != 0;

    U8 ones;                                         // bf16 1.0 x8 A-fragment
    ones.q = make_uint4(0x3F803F80u, 0x3F803F80u, 0x3F803F80u, 0x3F803F80u);

    // ---- stage V^T once for all heads (R3-verified 4-wave pattern):
    //      lane = k-row, wave picks 4 d-chunks.
    {
        for (int kr = lane; kr < nk; kr += 64) {
            #pragma unroll
            for (int ii = 0; ii < 4; ++ii) {
                int c = wid * 4 + ii;                // d-chunk 0..15
                uint4 v4 = *reinterpret_cast<const uint4*>(
                    &V[(size_t)(kst + kr) * DIM + c * 8]);
                uint32_t vv[4] = {v4.x, v4.y, v4.z, v4.w};
                #pragma unroll
                for (int m2 = 0; m2 < 4; ++m2) {
                    Vt[c * 8 + 2 * m2][kr]     = (ushort)(vv[m2] & 0xffffu);
                    Vt[c * 8 + 2 * m2 + 1][kr] = (ushort)(vv[m2] >> 16);
                }
            }
        }
        int pad = NKP - nk;
        for (int i = t; i < (pad << 7); i += 256) {
            int d = i & 127, col = nk + (i >> 7);
            Vt[d][col] = 0;
        }
    }
    __syncthreads();                                 // all waves see staged Vt

    for (int q0 = 0; q0 < nq; q0 += 16) {            // full q-loop per wave
        const int rq = qs + min(q0 + r16, nq - 1);
        bf16x8 bQ = *reinterpret_cast<const bf16x8*>(&Q[(size_t)rq * DIM + hcol + g * 8]);

        f32x4 oa0 = {0.f, 0.f, 0.f, 0.f}, oa1 = {0.f, 0.f, 0.f, 0.f};
        f32x4 la  = {0.f, 0.f, 0.f, 0.f};            // denominator accumulator

        // ---- full chunks: no masks, no clamps, no max machinery
        for (int ck = 0; ck < NFULL; ++ck) {
            const int k0 = ck * 32;
            bf16x8 aK0 = *reinterpret_cast<const bf16x8*>(
                &K[(size_t)(kst + k0 + r16) * DIM + hcol + g * 8]);
            bf16x8 aK1 = *reinterpret_cast<const bf16x8*>(
                &K[(size_t)(kst + k0 + 16 + r16) * DIM + hcol + g * 8]);
            f32x4 s0 = __builtin_amdgcn_mfma_f32_16x16x32_bf16(
                aK0, bQ, (f32x4){0.f, 0.f, 0.f, 0.f}, 0, 0, 0);
            f32x4 s1 = __builtin_amdgcn_mfma_f32_16x16x32_bf16(
                aK1, bQ, (f32x4){0.f, 0.f, 0.f, 0.f}, 0, 0, 0);

            float e[8];
            #pragma unroll
            for (int j = 0; j < 4; ++j) {
                e[j]     = __expf(s0[j]);            // Q pre-scaled
                e[4 + j] = __expf(s1[j]);
            }
            uint2 w0, w1;
            w0.x = pkcvt(e[0], e[1]);
            w0.y = pkcvt(e[2], e[3]);
            w1.x = pkcvt(e[4], e[5]);
            w1.y = pkcvt(e[6], e[7]);
            *reinterpret_cast<uint2*>(&Ps[wid][r16][4 * g]) = w0;
            *reinterpret_cast<uint2*>(&Ps[wid][r16][16 + 4 * g]) = w1;
            bf16x8 bP = *reinterpret_cast<const bf16x8*>(&Ps[wid][r16][g * 8]);

            U8 av0, av1;
            av0.u[0] = *reinterpret_cast<const uint2*>(&Vt[hcol + r16][k0 + g * 8]);
            av0.u[1] = *reinterpret_cast<const uint2*>(&Vt[hcol + r16][k0 + g * 8 + 4]);
            av1.u[0] = *reinterpret_cast<const uint2*>(&Vt[hcol + 16 + r16][k0 + g * 8]);
            av1.u[1] = *reinterpret_cast<const uint2*>(&Vt[hcol + 16 + r16][k0 + g * 8 + 4]);
            oa0 = __builtin_amdgcn_mfma_f32_16x16x32_bf16(av0.v, bP, oa0, 0, 0, 0);
            oa1 = __builtin_amdgcn_mfma_f32_16x16x32_bf16(av1.v, bP, oa1, 0, 0, 0);
            la  = __builtin_amdgcn_mfma_f32_16x16x32_bf16(ones.v, bP, la, 0, 0, 0);
        }

        // ---- tail chunk: clamped loads + e-masking (verified semantics)
        if (tail) {
            const int k0 = NFULL * 32;
            const int rk0 = kst + min(k0 + r16, nk - 1);
            const int rk1 = kst + min(k0 + 16 + r16, nk - 1);
            bf16x8 aK0 = *reinterpret_cast<const bf16x8*>(&K[(size_t)rk0 * DIM + hcol + g * 8]);
            bf16x8 aK1 = *reinterpret_cast<const bf16x8*>(&K[(size_t)rk1 * DIM + hcol + g * 8]);
            f32x4 s0 = __builtin_amdgcn_mfma_f32_16x16x32_bf16(
                aK0, bQ, (f32x4){0.f, 0.f, 0.f, 0.f}, 0, 0, 0);
            f32x4 s1 = __builtin_amdgcn_mfma_f32_16x16x32_bf16(
                aK1, bQ, (f32x4){0.f, 0.f, 0.f, 0.f}, 0, 0, 0);

            float e[8];
            #pragma unroll
            for (int j = 0; j < 4; ++j) {
                e[j]     = (k0 + 4 * g + j < nk)      ? __expf(s0[j]) : 0.f;
                e[4 + j] = (k0 + 16 + 4 * g + j < nk) ? __expf(s1[j]) : 0.f;
            }
            uint2 w0, w1;
            w0.x = pkcvt(e[0], e[1]);
            w0.y = pkcvt(e[2], e[3]);
            w1.x = pkcvt(e[4], e[5]);
            w1.y = pkcvt(e[6], e[7]);
            *reinterpret_cast<uint2*>(&Ps[wid][r16][4 * g]) = w0;
            *reinterpret_cast<uint2*>(&Ps[wid][r16][16 + 4 * g]) = w1;
            bf16x8 bP = *reinterpret_cast<const bf16x8*>(&Ps[wid][r16][g * 8]);

            U8 av0, av1;
            av0.u[0] = *reinterpret_cast<const uint2*>(&Vt[hcol + r16][k0 + g * 8]);
            av0.u[1] = *reinterpret_cast<const uint2*>(&Vt[hcol + r16][k0 + g * 8 + 4]);
            av1.u[0] = *reinterpret_cast<const uint2*>(&Vt[hcol + 16 + r16][k0 + g * 8]);
            av1.u[1] = *reinterpret_cast<const uint2*>(&Vt[hcol + 16 + r16][k0 + g * 8 + 4]);
            oa0 = __builtin_amdgcn_mfma_f32_16x16x32_bf16(av0.v, bP, oa0, 0, 0, 0);
            oa1 = __builtin_amdgcn_mfma_f32_16x16x32_bf16(av1.v, bP, oa1, 0, 0, 0);
            la  = __builtin_amdgcn_mfma_f32_16x16x32_bf16(ones.v, bP, la, 0, 0, 0);
        }

        if (q0 + r16 < nq) {
            float inv = 1.f / fmaxf(la[0], 1e-9f);   // l for q=r16, lane-local
            ushort* dst = &Q[(size_t)(qs + q0 + r16) * DIM + hcol];
            uint2 o0, o1;
            o0.x = pkcvt(oa0[0] * inv, oa0[1] * inv);
            o0.y = pkcvt(oa0[2] * inv, oa0[3] * inv);
            o1.x = pkcvt(oa1[0] * inv, oa1[1] * inv);
            o1.y = pkcvt(oa1[2] * inv, oa1[3] * inv);
            *reinterpret_cast<uint2*>(dst + 4 * g) = o0;
            *reinterpret_cast<uint2*>(dst + 16 + 4 * g) = o1;
        }
    }
}

// ---------------------------------------------------------------------------
// K3: MFMA out-projection + bias + residual + LayerNorm (unchanged, verified).
// ---------------------------------------------------------------------------
__global__ __launch_bounds__(256) void out_mfma(
    const ushort* __restrict__ qkv,
    const float* __restrict__ x_don, const float* __restrict__ x_acc,
    const ushort* __restrict__ wtg,
    const float* __restrict__ bo, const float* __restrict__ ln_g, const float* __restrict__ ln_b,
    float* __restrict__ out, int N)
{
    __shared__ ushort wt[128][WTP];
    const int t = threadIdx.x;
    const int lane = t & 63, wid = t >> 6;
    const int r16 = lane & 15, kg = lane >> 4;
    const int r0 = blockIdx.x * 128;                 // row in [0, 2N)
    const int wr0 = r0 + wid * 32;
    const ushort* attb = qkv + (r0 < N ? (size_t)0 : (size_t)2 * N * DIM); // slot0/slot3
    const float* xresb = (r0 < N) ? x_don : x_acc;
    const int rx0 = (r0 < N) ? wr0 : wr0 - N;

    const ushort* wsrc = wtg + ((size_t)3 << 14);    // Wo^T
    #pragma unroll
    for (int p = 0; p < 8; ++p) {
        int lin = (p * 256 + t) * 8;
        int c = lin >> 7, k = lin & 127;
        *reinterpret_cast<uint4*>(&wt[c][k]) =
            *reinterpret_cast<const uint4*>(&wsrc[c * DIM + k]);
    }

    U8 ab[2][4];
    #pragma unroll
    for (int rt = 0; rt < 2; ++rt)
        #pragma unroll
        for (int ks = 0; ks < 4; ++ks)
            ab[rt][ks].q = *reinterpret_cast<const uint4*>(
                &attb[(size_t)(wr0 + rt * 16 + r16) * DIM + ks * 32 + kg * 8]);

    __syncthreads();                                 // wt ready

    f32x4 acc[2][8];
    #pragma unroll
    for (int i = 0; i < 2; ++i)
        #pragma unroll
        for (int j = 0; j < 8; ++j) acc[i][j] = (f32x4){0.f, 0.f, 0.f, 0.f};

    #pragma unroll
    for (int ks = 0; ks < 4; ++ks)
        #pragma unroll
        for (int ct = 0; ct < 8; ++ct) {
            bf16x8 bfr = *reinterpret_cast<const bf16x8*>(
                &wt[ct * 16 + r16][ks * 32 + kg * 8]);
            acc[0][ct] = __builtin_amdgcn_mfma_f32_16x16x32_bf16(ab[0][ks].v, bfr, acc[0][ct], 0, 0, 0);
            acc[1][ct] = __builtin_amdgcn_mfma_f32_16x16x32_bf16(ab[1][ks].v, bfr, acc[1][ct], 0, 0, 0);
        }

    float bo8[8], g8[8], be8[8];
    #pragma unroll
    for (int ct = 0; ct < 8; ++ct) {
        int c = ct * 16 + r16;
        bo8[ct] = bo[c]; g8[ct] = ln_g[c]; be8[ct] = ln_b[c];
    }

    #pragma unroll
    for (int rt = 0; rt < 2; ++rt) {
        #pragma unroll
        for (int j = 0; j < 4; ++j) {
            int rl = rt * 16 + kg * 4 + j;           // VERIFIED: D row -> att-row
            const float* resr = &xresb[(size_t)(rx0 + rl) * DIM];
            float y[8];
            float s = 0.f, ss = 0.f;
            #pragma unroll
            for (int ct = 0; ct < 8; ++ct) {
                float v = acc[rt][ct][j] + bo8[ct] + resr[ct * 16 + r16];
                y[ct] = v; s += v; ss += v * v;
            }
            #pragma unroll
            for (int mk2 = 1; mk2 < 16; mk2 <<= 1) {
                s  += __shfl_xor(s, mk2);
                ss += __shfl_xor(ss, mk2);
            }
            float mu   = s * (1.f / 128.f);
            float var  = ss * (1.f / 128.f) - mu * mu;
            float rinv = rsqrtf(var + LN_EPS);
            #pragma unroll
            for (int ct = 0; ct < 8; ++ct)
                out[(size_t)(wr0 + rl) * DIM + ct * 16 + r16] =
                    (y[ct] - mu) * rinv * g8[ct] + be8[ct];
        }
    }
}

// ---------------------------------------------------------------------------
extern "C" void kernel_launch(void* const* d_in, const int* in_sizes, int n_in,
                              void* d_out, int out_size, void* d_ws, size_t ws_size,
                              hipStream_t stream)
{
    const float* x_don = (const float*)d_in[0];
    const float* x_acc = (const float*)d_in[1];
    const float* Wq = (const float*)d_in[2];  const float* bq = (const float*)d_in[3];
    const float* Wk = (const float*)d_in[4];  const float* bk = (const float*)d_in[5];
    const float* Wv = (const float*)d_in[6];  const float* bv = (const float*)d_in[7];
    const float* Wo = (const float*)d_in[8];  const float* bo = (const float*)d_in[9];
    const float* ln_g = (const float*)d_in[10]; const float* ln_b = (const float*)d_in[11];
    const int* batch_don = (const int*)d_in[12];
    const int* batch_acc = (const int*)d_in[13];
    const int N = in_sizes[0] / DIM;          // 65536
    float* out = (float*)d_out;

    char* ws = (char*)d_ws;
    int* starts = (int*)ws;                           // 2*NB ints
    int* counts = starts + 2 * NB;                    // 2*NB ints
    ushort* qkv = (ushort*)(ws + 16384);              // 6 x N*DIM bf16 (96MB)
    ushort* wtg = (ushort*)(ws + 16384 + (size_t)6 * N * DIM * 2);  // 4 x 16384 bf16

    setup_kernel<<<256, 256, 0, stream>>>(Wq, Wk, Wv, Wo, wtg,
                                          batch_don, batch_acc, starts, counts, N);

    dim3 gproj(N / 128, 2);
    proj_mfma<<<gproj, 512, 0, stream>>>(x_don, x_acc, wtg, bq, bk, bv, qkv, N);

    dim3 gattn(NB, 2);
    attn_mfma<<<gattn, 256, 0, stream>>>(qkv, starts, counts, N);

    out_mfma<<<(2 * N) / 128, 256, 0, stream>>>(qkv, x_don, x_acc, wtg,
                                                bo, ln_g, ln_b, out, N);
}

// Round 21
// 115.716 us; speedup vs baseline: 1.0204x; 1.0204x over previous
//
#include <hip/hip_runtime.h>
#include <hip/hip_bf16.h>
#include <stdint.h>

#define NB 1024          // B molecules
#define LMAX 160
#define DIM 128
#define NH 4
#define HDIM 32
#define ATT_SCALE 0.1767766952966369f   // 32^-0.5
#define LN_EPS 1e-5f
#define VTP 164          // V^T LDS pitch (u16): conflict-free b64 reads
#define PSP 40           // P LDS pitch (u16)
#define WTP 136          // W^T LDS pitch (u16): 272B rows, 16B-aligned, 2-way banks

typedef __attribute__((ext_vector_type(8))) short bf16x8;
typedef __attribute__((ext_vector_type(4))) float f32x4;

union U8 { uint2 u[2]; uint4 q; bf16x8 v; };

__device__ __forceinline__ ushort f2bf(float f) {
    uint32_t x = __float_as_uint(f);
    x += 0x7fffu + ((x >> 16) & 1u);   // round-to-nearest-even
    return (ushort)(x >> 16);
}
__device__ __forceinline__ uint32_t pk2bf(float a, float b) {
    return (uint32_t)f2bf(a) | ((uint32_t)f2bf(b) << 16);
}
// HW-packed bf16 conversion (v_cvt_pk_bf16_f32): 1 op for 2 values.
__device__ __forceinline__ uint32_t pkcvt(float a, float b) {
    __hip_bfloat162 h = __float22bfloat162_rn(make_float2(a, b));
    return *reinterpret_cast<uint32_t*>(&h);
}

// Workgroup barrier without the vmcnt(0) store drain (R13-verified safe).
__device__ __forceinline__ void wgbar_noflush() {
    asm volatile("s_waitcnt lgkmcnt(0)" ::: "memory");
    __builtin_amdgcn_s_barrier();
    asm volatile("" ::: "memory");
}

// ---------------------------------------------------------------------------
// K0: merged setup (weights transpose + segment binary search).
// ---------------------------------------------------------------------------
__global__ void setup_kernel(const float* __restrict__ Wq, const float* __restrict__ Wk,
                             const float* __restrict__ Wv, const float* __restrict__ Wo,
                             ushort* __restrict__ wtg,
                             const int* __restrict__ bd, const int* __restrict__ ba,
                             int* __restrict__ starts, int* __restrict__ counts, int N)
{
    int t = blockIdx.x * blockDim.x + threadIdx.x;   // 65536 threads
    {   // weight transpose (all threads)
        int m = t >> 14;
        int idx = t & 16383;
        int k = idx >> 7, c = idx & 127;
        const float* W = (m == 0) ? Wq : (m == 1) ? Wk : (m == 2) ? Wv : Wo;
        wtg[(m << 14) + c * DIM + k] = f2bf(W[idx]);
    }
    if (t < 2 * NB) {    // segment search (first 2048 threads)
        int side = t >> 10;
        int b = t & (NB - 1);
        const int* arr = side ? ba : bd;
        int lo = 0, hi = N;
        while (lo < hi) { int mid = (lo + hi) >> 1; if (arr[mid] < b) lo = mid + 1; else hi = mid; }
        int st = lo;
        hi = N;
        while (lo < hi) { int mid = (lo + hi) >> 1; if (arr[mid] < b + 1) lo = mid + 1; else hi = mid; }
        starts[t] = st;
        counts[t] = lo - st;
    }
}

// ---------------------------------------------------------------------------
// K1: MFMA projections, 8-wave blocks, coalesced LDS-repack epilogue (R19
// verified).  Q (w==0) written PRE-SCALED by ATT_SCALE (R20-verified).
// ---------------------------------------------------------------------------
__global__ __launch_bounds__(512) void proj_mfma(
    const float* __restrict__ x_don, const float* __restrict__ x_acc,
    const ushort* __restrict__ wtg,
    const float* __restrict__ bq, const float* __restrict__ bk, const float* __restrict__ bv,
    ushort* __restrict__ qkv, int N)
{
    __shared__ ushort wt[128][WTP];
    const int side = blockIdx.y;
    const float* x = side ? x_acc : x_don;
    const int t = threadIdx.x;
    const int lane = t & 63, wid = t >> 6;           // 8 waves
    const int r16 = lane & 15, kg = lane >> 4;
    const int wr0 = blockIdx.x * 128 + wid * 16;     // this wave's 16 rows

    float4 raw[4][2];
    {
        const float* xr = &x[(size_t)(wr0 + r16) * DIM + kg * 8];
        #pragma unroll
        for (int ks = 0; ks < 4; ++ks) {
            raw[ks][0] = *reinterpret_cast<const float4*>(xr + ks * 32);
            raw[ks][1] = *reinterpret_cast<const float4*>(xr + ks * 32 + 4);
        }
    }
    U8 xb[4];
    #pragma unroll
    for (int ks = 0; ks < 4; ++ks) {
        xb[ks].u[0].x = pk2bf(raw[ks][0].x, raw[ks][0].y);
        xb[ks].u[0].y = pk2bf(raw[ks][0].z, raw[ks][0].w);
        xb[ks].u[1].x = pk2bf(raw[ks][1].x, raw[ks][1].y);
        xb[ks].u[1].y = pk2bf(raw[ks][1].z, raw[ks][1].w);
    }

    for (int w = 0; w < 3; ++w) {
        if (w) wgbar_noflush();                      // repack reads done, wt free
        const ushort* wsrc = wtg + ((size_t)w << 14);
        #pragma unroll
        for (int p = 0; p < 4; ++p) {                // 512 thr x 4 x 8 u16 = 16384
            int lin = (p * 512 + t) * 8;
            int c = lin >> 7, k = lin & 127;
            *reinterpret_cast<uint4*>(&wt[c][k]) =
                *reinterpret_cast<const uint4*>(&wsrc[c * DIM + k]);
        }
        wgbar_noflush();                             // wt staged

        f32x4 acc[8];
        #pragma unroll
        for (int j = 0; j < 8; ++j) acc[j] = (f32x4){0.f, 0.f, 0.f, 0.f};

        #pragma unroll
        for (int ks = 0; ks < 4; ++ks)
            #pragma unroll
            for (int ct = 0; ct < 8; ++ct) {
                bf16x8 bfr = *reinterpret_cast<const bf16x8*>(
                    &wt[ct * 16 + r16][ks * 32 + kg * 8]);
                acc[ct] = __builtin_amdgcn_mfma_f32_16x16x32_bf16(xb[ks].v, bfr, acc[ct], 0, 0, 0);
            }

        const float* bias = (w == 0) ? bq : (w == 1) ? bk : bv;
        const float sc = (w == 0) ? ATT_SCALE : 1.f; // pre-scale Q
        float b8[8];
        #pragma unroll
        for (int ct = 0; ct < 8; ++ct) b8[ct] = bias[ct * 16 + r16];

        wgbar_noflush();                             // C: all waves done reading wt

        // ---- scatter into own 16-row quarter (VERIFIED D layout)
        #pragma unroll
        for (int ct = 0; ct < 8; ++ct)
            #pragma unroll
            for (int j = 0; j < 4; ++j)
                wt[wid * 16 + kg * 4 + j][ct * 16 + r16] =
                    f2bf((acc[ct][j] + b8[ct]) * sc);

        // ---- read back full rows (same-wave DS ordering) -> dense dwordx4
        ushort* outp = qkv + (size_t)(side * 3 + w) * N * DIM;
        const int lr4 = lane >> 4;                   // 0..3
        const int c8 = (lane & 15) * 8;              // u16 col (16B chunk)
        #pragma unroll
        for (int ps = 0; ps < 4; ++ps) {
            int lr = ps * 4 + lr4;                   // local row 0..15
            uint4 vv = *reinterpret_cast<const uint4*>(&wt[wid * 16 + lr][c8]);
            *reinterpret_cast<uint4*>(&outp[(size_t)(wr0 + lr) * DIM + c8]) = vv;
        }
    }
}

// ---------------------------------------------------------------------------
// K2: swapped-operand MFMA cross attention -- R19-VERIFIED SHAPE (grid
// (B,2,NH), 4 waves/block, q-tile split, 15.6KB LDS, Occ ~44%) with slim
// softmax, ones-MFMA denominator, pkcvt packing, and pre-scaled Q (the only
// delta vs R19: exp(s) instead of exp(s*SCALE)).
// ---------------------------------------------------------------------------
__global__ __launch_bounds__(256) void attn_mfma(
    ushort* __restrict__ qkv,
    const int* __restrict__ starts, const int* __restrict__ counts, int N)
{
    __shared__ __align__(16) ushort Vt[HDIM][VTP];   // V^T slice (shared by all waves)
    __shared__ __align__(16) ushort Ps[4][16][PSP];  // P round-trip tile, per wave
    const int b = blockIdx.x, dir = blockIdx.y;
    const int hcol = blockIdx.z * HDIM;
    const int qside = dir, kside = 1 - dir;
    const int qs = starts[qside * NB + b];
    const int nq = counts[qside * NB + b];
    if (nq == 0) return;
    const int kst = starts[kside * NB + b];
    const int nk = min(counts[kside * NB + b], LMAX);
    ushort* Q = qkv + (size_t)(qside * 3) * N * DIM;
    const ushort* K = qkv + (size_t)(kside * 3 + 1) * N * DIM;
    const ushort* V = qkv + (size_t)(kside * 3 + 2) * N * DIM;
    const int t = threadIdx.x;                       // 0..255
    const int lane = t & 63, wid = t >> 6;
    const int r16 = lane & 15, g = lane >> 4;

    const int NCK = (nk + 31) >> 5;
    const int NKP = NCK << 5;
    const int NFULL = nk >> 5;                       // unmasked 32-k chunks
    const bool tail = (nk & 31) != 0;

    U8 ones;                                         // bf16 1.0 x8 A-fragment
    ones.q = make_uint4(0x3F803F80u, 0x3F803F80u, 0x3F803F80u, 0x3F803F80u);

    // ---- stage V^T cooperatively with 256 threads (R4-verified layout)
    {
        const int krl = t >> 2, c = t & 3;           // 64 rows per sweep
        for (int base = 0; base < nk; base += 64) {
            int kr = base + krl;
            if (kr < nk) {
                uint4 v4 = *reinterpret_cast<const uint4*>(
                    &V[(size_t)(kst + kr) * DIM + hcol + c * 8]);
                uint32_t vv[4] = {v4.x, v4.y, v4.z, v4.w};
                #pragma unroll
                for (int m2 = 0; m2 < 4; ++m2) {
                    Vt[c * 8 + 2 * m2][kr]     = (ushort)(vv[m2] & 0xffffu);
                    Vt[c * 8 + 2 * m2 + 1][kr] = (ushort)(vv[m2] >> 16);
                }
            }
        }
        int pad = NKP - nk;
        for (int i = t; i < (pad << 5); i += 256) {
            int d = i & 31, col = nk + (i >> 5);
            Vt[d][col] = 0;
        }
    }
    __syncthreads();                                 // all waves see staged Vt

    for (int q0 = wid * 16; q0 < nq; q0 += 64) {     // disjoint q tiles per wave
        const int rq = qs + min(q0 + r16, nq - 1);
        bf16x8 bQ = *reinterpret_cast<const bf16x8*>(&Q[(size_t)rq * DIM + hcol + g * 8]);

        f32x4 oa0 = {0.f, 0.f, 0.f, 0.f}, oa1 = {0.f, 0.f, 0.f, 0.f};
        f32x4 la  = {0.f, 0.f, 0.f, 0.f};            // denominator accumulator

        // ---- full chunks: no masks, no clamps, no max machinery
        for (int ck = 0; ck < NFULL; ++ck) {
            const int k0 = ck * 32;
            bf16x8 aK0 = *reinterpret_cast<const bf16x8*>(
                &K[(size_t)(kst + k0 + r16) * DIM + hcol + g * 8]);
            bf16x8 aK1 = *reinterpret_cast<const bf16x8*>(
                &K[(size_t)(kst + k0 + 16 + r16) * DIM + hcol + g * 8]);
            f32x4 s0 = __builtin_amdgcn_mfma_f32_16x16x32_bf16(
                aK0, bQ, (f32x4){0.f, 0.f, 0.f, 0.f}, 0, 0, 0);
            f32x4 s1 = __builtin_amdgcn_mfma_f32_16x16x32_bf16(
                aK1, bQ, (f32x4){0.f, 0.f, 0.f, 0.f}, 0, 0, 0);

            float e[8];
            #pragma unroll
            for (int j = 0; j < 4; ++j) {
                e[j]     = __expf(s0[j]);            // Q pre-scaled
                e[4 + j] = __expf(s1[j]);
            }
            uint2 w0, w1;
            w0.x = pkcvt(e[0], e[1]);
            w0.y = pkcvt(e[2], e[3]);
            w1.x = pkcvt(e[4], e[5]);
            w1.y = pkcvt(e[6], e[7]);
            *reinterpret_cast<uint2*>(&Ps[wid][r16][4 * g]) = w0;
            *reinterpret_cast<uint2*>(&Ps[wid][r16][16 + 4 * g]) = w1;
            bf16x8 bP = *reinterpret_cast<const bf16x8*>(&Ps[wid][r16][g * 8]);

            U8 av0, av1;
            av0.u[0] = *reinterpret_cast<const uint2*>(&Vt[r16][k0 + g * 8]);
            av0.u[1] = *reinterpret_cast<const uint2*>(&Vt[r16][k0 + g * 8 + 4]);
            av1.u[0] = *reinterpret_cast<const uint2*>(&Vt[16 + r16][k0 + g * 8]);
            av1.u[1] = *reinterpret_cast<const uint2*>(&Vt[16 + r16][k0 + g * 8 + 4]);
            oa0 = __builtin_amdgcn_mfma_f32_16x16x32_bf16(av0.v, bP, oa0, 0, 0, 0);
            oa1 = __builtin_amdgcn_mfma_f32_16x16x32_bf16(av1.v, bP, oa1, 0, 0, 0);
            la  = __builtin_amdgcn_mfma_f32_16x16x32_bf16(ones.v, bP, la, 0, 0, 0);
        }

        // ---- tail chunk: clamped loads + e-masking (verified semantics)
        if (tail) {
            const int k0 = NFULL * 32;
            const int rk0 = kst + min(k0 + r16, nk - 1);
            const int rk1 = kst + min(k0 + 16 + r16, nk - 1);
            bf16x8 aK0 = *reinterpret_cast<const bf16x8*>(&K[(size_t)rk0 * DIM + hcol + g * 8]);
            bf16x8 aK1 = *reinterpret_cast<const bf16x8*>(&K[(size_t)rk1 * DIM + hcol + g * 8]);
            f32x4 s0 = __builtin_amdgcn_mfma_f32_16x16x32_bf16(
                aK0, bQ, (f32x4){0.f, 0.f, 0.f, 0.f}, 0, 0, 0);
            f32x4 s1 = __builtin_amdgcn_mfma_f32_16x16x32_bf16(
                aK1, bQ, (f32x4){0.f, 0.f, 0.f, 0.f}, 0, 0, 0);

            float e[8];
            #pragma unroll
            for (int j = 0; j < 4; ++j) {
                e[j]     = (k0 + 4 * g + j < nk)      ? __expf(s0[j]) : 0.f;
                e[4 + j] = (k0 + 16 + 4 * g + j < nk) ? __expf(s1[j]) : 0.f;
            }
            uint2 w0, w1;
            w0.x = pkcvt(e[0], e[1]);
            w0.y = pkcvt(e[2], e[3]);
            w1.x = pkcvt(e[4], e[5]);
            w1.y = pkcvt(e[6], e[7]);
            *reinterpret_cast<uint2*>(&Ps[wid][r16][4 * g]) = w0;
            *reinterpret_cast<uint2*>(&Ps[wid][r16][16 + 4 * g]) = w1;
            bf16x8 bP = *reinterpret_cast<const bf16x8*>(&Ps[wid][r16][g * 8]);

            U8 av0, av1;
            av0.u[0] = *reinterpret_cast<const uint2*>(&Vt[r16][k0 + g * 8]);
            av0.u[1] = *reinterpret_cast<const uint2*>(&Vt[r16][k0 + g * 8 + 4]);
            av1.u[0] = *reinterpret_cast<const uint2*>(&Vt[16 + r16][k0 + g * 8]);
            av1.u[1] = *reinterpret_cast<const uint2*>(&Vt[16 + r16][k0 + g * 8 + 4]);
            oa0 = __builtin_amdgcn_mfma_f32_16x16x32_bf16(av0.v, bP, oa0, 0, 0, 0);
            oa1 = __builtin_amdgcn_mfma_f32_16x16x32_bf16(av1.v, bP, oa1, 0, 0, 0);
            la  = __builtin_amdgcn_mfma_f32_16x16x32_bf16(ones.v, bP, la, 0, 0, 0);
        }

        if (q0 + r16 < nq) {
            float inv = 1.f / fmaxf(la[0], 1e-9f);   // l for q=r16, lane-local
            ushort* dst = &Q[(size_t)(qs + q0 + r16) * DIM + hcol];
            uint2 o0, o1;
            o0.x = pkcvt(oa0[0] * inv, oa0[1] * inv);
            o0.y = pkcvt(oa0[2] * inv, oa0[3] * inv);
            o1.x = pkcvt(oa1[0] * inv, oa1[1] * inv);
            o1.y = pkcvt(oa1[2] * inv, oa1[3] * inv);
            *reinterpret_cast<uint2*>(dst + 4 * g) = o0;
            *reinterpret_cast<uint2*>(dst + 16 + 4 * g) = o1;
        }
    }
}

// ---------------------------------------------------------------------------
// K3: MFMA out-projection + bias + residual + LayerNorm (unchanged, verified).
// ---------------------------------------------------------------------------
__global__ __launch_bounds__(256) void out_mfma(
    const ushort* __restrict__ qkv,
    const float* __restrict__ x_don, const float* __restrict__ x_acc,
    const ushort* __restrict__ wtg,
    const float* __restrict__ bo, const float* __restrict__ ln_g, const float* __restrict__ ln_b,
    float* __restrict__ out, int N)
{
    __shared__ ushort wt[128][WTP];
    const int t = threadIdx.x;
    const int lane = t & 63, wid = t >> 6;
    const int r16 = lane & 15, kg = lane >> 4;
    const int r0 = blockIdx.x * 128;                 // row in [0, 2N)
    const int wr0 = r0 + wid * 32;
    const ushort* attb = qkv + (r0 < N ? (size_t)0 : (size_t)2 * N * DIM); // slot0/slot3
    const float* xresb = (r0 < N) ? x_don : x_acc;
    const int rx0 = (r0 < N) ? wr0 : wr0 - N;

    const ushort* wsrc = wtg + ((size_t)3 << 14);    // Wo^T
    #pragma unroll
    for (int p = 0; p < 8; ++p) {
        int lin = (p * 256 + t) * 8;
        int c = lin >> 7, k = lin & 127;
        *reinterpret_cast<uint4*>(&wt[c][k]) =
            *reinterpret_cast<const uint4*>(&wsrc[c * DIM + k]);
    }

    U8 ab[2][4];
    #pragma unroll
    for (int rt = 0; rt < 2; ++rt)
        #pragma unroll
        for (int ks = 0; ks < 4; ++ks)
            ab[rt][ks].q = *reinterpret_cast<const uint4*>(
                &attb[(size_t)(wr0 + rt * 16 + r16) * DIM + ks * 32 + kg * 8]);

    __syncthreads();                                 // wt ready

    f32x4 acc[2][8];
    #pragma unroll
    for (int i = 0; i < 2; ++i)
        #pragma unroll
        for (int j = 0; j < 8; ++j) acc[i][j] = (f32x4){0.f, 0.f, 0.f, 0.f};

    #pragma unroll
    for (int ks = 0; ks < 4; ++ks)
        #pragma unroll
        for (int ct = 0; ct < 8; ++ct) {
            bf16x8 bfr = *reinterpret_cast<const bf16x8*>(
                &wt[ct * 16 + r16][ks * 32 + kg * 8]);
            acc[0][ct] = __builtin_amdgcn_mfma_f32_16x16x32_bf16(ab[0][ks].v, bfr, acc[0][ct], 0, 0, 0);
            acc[1][ct] = __builtin_amdgcn_mfma_f32_16x16x32_bf16(ab[1][ks].v, bfr, acc[1][ct], 0, 0, 0);
        }

    float bo8[8], g8[8], be8[8];
    #pragma unroll
    for (int ct = 0; ct < 8; ++ct) {
        int c = ct * 16 + r16;
        bo8[ct] = bo[c]; g8[ct] = ln_g[c]; be8[ct] = ln_b[c];
    }

    #pragma unroll
    for (int rt = 0; rt < 2; ++rt) {
        #pragma unroll
        for (int j = 0; j < 4; ++j) {
            int rl = rt * 16 + kg * 4 + j;           // VERIFIED: D row -> att-row
            const float* resr = &xresb[(size_t)(rx0 + rl) * DIM];
            float y[8];
            float s = 0.f, ss = 0.f;
            #pragma unroll
            for (int ct = 0; ct < 8; ++ct) {
                float v = acc[rt][ct][j] + bo8[ct] + resr[ct * 16 + r16];
                y[ct] = v; s += v; ss += v * v;
            }
            #pragma unroll
            for (int mk2 = 1; mk2 < 16; mk2 <<= 1) {
                s  += __shfl_xor(s, mk2);
                ss += __shfl_xor(ss, mk2);
            }
            float mu   = s * (1.f / 128.f);
            float var  = ss * (1.f / 128.f) - mu * mu;
            float rinv = rsqrtf(var + LN_EPS);
            #pragma unroll
            for (int ct = 0; ct < 8; ++ct)
                out[(size_t)(wr0 + rl) * DIM + ct * 16 + r16] =
                    (y[ct] - mu) * rinv * g8[ct] + be8[ct];
        }
    }
}

// ---------------------------------------------------------------------------
extern "C" void kernel_launch(void* const* d_in, const int* in_sizes, int n_in,
                              void* d_out, int out_size, void* d_ws, size_t ws_size,
                              hipStream_t stream)
{
    const float* x_don = (const float*)d_in[0];
    const float* x_acc = (const float*)d_in[1];
    const float* Wq = (const float*)d_in[2];  const float* bq = (const float*)d_in[3];
    const float* Wk = (const float*)d_in[4];  const float* bk = (const float*)d_in[5];
    const float* Wv = (const float*)d_in[6];  const float* bv = (const float*)d_in[7];
    const float* Wo = (const float*)d_in[8];  const float* bo = (const float*)d_in[9];
    const float* ln_g = (const float*)d_in[10]; const float* ln_b = (const float*)d_in[11];
    const int* batch_don = (const int*)d_in[12];
    const int* batch_acc = (const int*)d_in[13];
    const int N = in_sizes[0] / DIM;          // 65536
    float* out = (float*)d_out;

    char* ws = (char*)d_ws;
    int* starts = (int*)ws;                           // 2*NB ints
    int* counts = starts + 2 * NB;                    // 2*NB ints
    ushort* qkv = (ushort*)(ws + 16384);              // 6 x N*DIM bf16 (96MB)
    ushort* wtg = (ushort*)(ws + 16384 + (size_t)6 * N * DIM * 2);  // 4 x 16384 bf16

    setup_kernel<<<256, 256, 0, stream>>>(Wq, Wk, Wv, Wo, wtg,
                                          batch_don, batch_acc, starts, counts, N);

    dim3 gproj(N / 128, 2);
    proj_mfma<<<gproj, 512, 0, stream>>>(x_don, x_acc, wtg, bq, bk, bv, qkv, N);

    dim3 gattn(NB, 2, NH);
    attn_mfma<<<gattn, 256, 0, stream>>>(qkv, starts, counts, N);

    out_mfma<<<(2 * N) / 128, 256, 0, stream>>>(qkv, x_don, x_acc, wtg,
                                                bo, ln_g, ln_b, out, N);
}